// Round 1
// baseline (4358.123 us; speedup 1.0000x reference)
//
#include <hip/hip_runtime.h>
#include <hip/hip_bf16.h>

#define DINLINE __device__ __forceinline__

// ---------------- reduction helper ----------------
DINLINE void wave_red2(float& s, float& s2) {
  for (int o = 32; o > 0; o >>= 1) { s += __shfl_down(s, o); s2 += __shfl_down(s2, o); }
}

// ---------------- small kernels ----------------

// ctx_mean[b][d] = mean over t of context[b][t][d]
__global__ void k_ctx_mean(const float* __restrict__ ctx, float* __restrict__ cmean) {
  int b = blockIdx.x;
  int d = blockIdx.y * 256 + threadIdx.x;
  const float* p = ctx + (size_t)b * 256 * 1024 + d;
  float s = 0.f;
  for (int t = 0; t < 256; ++t) s += p[(size_t)t * 1024];
  cmean[b * 1024 + d] = s * (1.f / 256.f);
}

// GroupNorm stats for ctx_map: per (b,g) over 32 channels x 256 positions
__global__ void k_cn_stats(const float* __restrict__ ctx, const float* __restrict__ cmean,
                           const int* __restrict__ cond, float* __restrict__ stats) {
  int bg = blockIdx.x; int b = bg >> 5, g = bg & 31;
  bool cf = cond[b] != 0;
  float s = 0.f, s2 = 0.f;
  for (int idx = threadIdx.x; idx < 8192; idx += 256) {
    int t = idx >> 5, c = idx & 31;
    float v = cf ? ctx[((size_t)b * 256 + t) * 1024 + g * 32 + c] : cmean[b * 1024 + g * 32 + c];
    s += v; s2 += v * v;
  }
  wave_red2(s, s2);
  __shared__ float sh[4][2];
  int lane = threadIdx.x & 63, w = threadIdx.x >> 6;
  if (lane == 0) { sh[w][0] = s; sh[w][1] = s2; }
  __syncthreads();
  if (threadIdx.x == 0) {
    s = sh[0][0] + sh[1][0] + sh[2][0] + sh[3][0];
    s2 = sh[0][1] + sh[1][1] + sh[2][1] + sh[3][1];
    float m = s * (1.f / 8192.f);
    float var = s2 * (1.f / 8192.f) - m * m;
    stats[bg * 2] = m;
    stats[bg * 2 + 1] = 1.f / sqrtf(var + 1e-6f);
  }
}

// stats over contiguous runs of 810 floats (10 channels x 81 positions), for ln / xa GN
__global__ void k_stats810(const float* __restrict__ src, float* __restrict__ stats, float eps) {
  int bg = blockIdx.x;
  const float* p = src + (size_t)bg * 810;
  float s = 0.f, s2 = 0.f;
  for (int i = threadIdx.x; i < 810; i += 256) { float v = p[i]; s += v; s2 += v * v; }
  wave_red2(s, s2);
  __shared__ float sh[4][2];
  int lane = threadIdx.x & 63, w = threadIdx.x >> 6;
  if (lane == 0) { sh[w][0] = s; sh[w][1] = s2; }
  __syncthreads();
  if (threadIdx.x == 0) {
    s = sh[0][0] + sh[1][0] + sh[2][0] + sh[3][0];
    s2 = sh[0][1] + sh[1][1] + sh[2][1] + sh[3][1];
    float m = s * (1.f / 810.f);
    float var = s2 * (1.f / 810.f) - m * m;
    stats[bg * 2] = m;
    stats[bg * 2 + 1] = 1.f / sqrtf(var + eps);
  }
}

// ROI align: roix[b][c][p] (p = iy*9+ix)
__global__ void k_roi(const float* __restrict__ gx, const float* __restrict__ bbox,
                      float* __restrict__ roix) {
  int b = blockIdx.x;
  __shared__ int iy0[9], iy1[9], ix0[9], ix1[9];
  __shared__ float fly[9], flx[9];
  int t = threadIdx.x;
  if (t < 9) {
    float x1 = bbox[b * 4 + 0], y1 = bbox[b * 4 + 1], x2 = bbox[b * 4 + 2], y2 = bbox[b * 4 + 3];
    float rw = fmaxf(x2 - x1, 1.f), rh = fmaxf(y2 - y1, 1.f);
    float ctr = ((float)t + 0.5f) / 9.0f;
    float ys = y1 + ctr * rh;
    float yc = fminf(fmaxf(ys, 0.f), 63.f);
    int y0 = (int)floorf(yc);
    iy0[t] = y0; iy1[t] = min(y0 + 1, 63); fly[t] = yc - (float)y0;
    float xs = x1 + ctr * rw;
    float xc = fminf(fmaxf(xs, 0.f), 63.f);
    int x0 = (int)floorf(xc);
    ix0[t] = x0; ix1[t] = min(x0 + 1, 63); flx[t] = xc - (float)x0;
  }
  __syncthreads();
  for (int idx = t; idx < 320 * 81; idx += 256) {
    int c = idx / 81, p = idx - c * 81;
    int py = p / 9, px = p - py * 9;
    const float* img = gx + ((size_t)b * 320 + c) * 4096;
    float ly = fly[py], lx = flx[px];
    float v00 = img[iy0[py] * 64 + ix0[px]];
    float v01 = img[iy0[py] * 64 + ix1[px]];
    float v10 = img[iy1[py] * 64 + ix0[px]];
    float v11 = img[iy1[py] * 64 + ix1[px]];
    float val = v00 * (1.f - ly) * (1.f - lx) + v01 * (1.f - ly) * lx +
                v10 * ly * (1.f - lx) + v11 * ly * lx;
    roix[((size_t)b * 320 + c) * 81 + p] = val;
  }
}

// row softmax over 256 (one block per row of 256, 256 threads)
__global__ void k_softmax(float* __restrict__ a) {
  size_t row = blockIdx.x;
  float* p = a + row * 256;
  int t = threadIdx.x;
  float v = p[t];
  float m = v;
  for (int o = 32; o > 0; o >>= 1) m = fmaxf(m, __shfl_down(m, o));
  __shared__ float sm[4], ss[4];
  if ((t & 63) == 0) sm[t >> 6] = m;
  __syncthreads();
  m = fmaxf(fmaxf(sm[0], sm[1]), fmaxf(sm[2], sm[3]));
  float e = expf(v - m);
  float s = e;
  for (int o = 32; o > 0; o >>= 1) s += __shfl_down(s, o);
  if ((t & 63) == 0) ss[t >> 6] = s;
  __syncthreads();
  s = ss[0] + ss[1] + ss[2] + ss[3];
  p[t] = e / s;
}

// x_local = gn(xa)*sg + sb   (all [b][c][p] layout)
__global__ void k_combine(const float* __restrict__ xa, const float* __restrict__ st,
                          const float* __restrict__ sg, const float* __restrict__ sb,
                          float* __restrict__ xl) {
  int idx = blockIdx.x * 256 + threadIdx.x;
  if (idx >= 32 * 320 * 81) return;
  int bc = idx / 81;
  int c = bc % 320, b = bc / 320;
  int g = c / 10;
  float m = st[(b * 32 + g) * 2], rs = st[(b * 32 + g) * 2 + 1];
  float v = (xa[idx] - m) * rs;
  xl[idx] = v * sg[idx] + sb[idx];
}

// out = global_x + nearest-paste(x_local) into bbox region
__global__ void k_paste(const float* __restrict__ gx, const float* __restrict__ bbox,
                        const float* __restrict__ xl, float* __restrict__ out) {
  int bc = blockIdx.x;
  int b = bc / 320;
  __shared__ int sy[64], sx[64];
  __shared__ unsigned char my[64], mx[64];
  int x1b = (int)floorf(bbox[b * 4 + 0] * 64.f);
  int y1b = (int)floorf(bbox[b * 4 + 1] * 64.f);
  int x2b = max((int)floorf(bbox[b * 4 + 2] * 64.f), x1b + 1);
  int y2b = max((int)floorf(bbox[b * 4 + 3] * 64.f), y1b + 1);
  int t = threadIdx.x;
  if (t < 64) {
    int jy = t - y1b, oh = y2b - y1b;
    my[t] = (jy >= 0 && t < y2b) ? 1 : 0;
    sy[t] = my[t] ? min(jy * 9 / oh, 8) : 0;
    int jx = t - x1b, ow = x2b - x1b;
    mx[t] = (jx >= 0 && t < x2b) ? 1 : 0;
    sx[t] = mx[t] ? min(jx * 9 / ow, 8) : 0;
  }
  __syncthreads();
  size_t base = (size_t)bc * 4096;
  const float* xlb = xl + (size_t)bc * 81;
  for (int idx = t; idx < 4096; idx += 256) {
    int y = idx >> 6, x = idx & 63;
    float add = (my[y] && mx[x]) ? xlb[sy[y] * 9 + sx[x]] : 0.f;
    out[base + idx] = gx[base + idx] + add;
  }
}

// ---------------- generic tiled GEMM: C[b,i,j] = sum_k A(b,i,k)*B(b,j,k) ----------------

struct AfK {  // normalized ctx_map rows, [t][d] native context layout
  const float* ctx; const float* cmean; const float* st; const float* g; const float* bt; const int* cond;
  DINLINE float operator()(int b, int i, int k) const {
    float v = cond[b] ? ctx[((size_t)b * 256 + i) * 1024 + k] : cmean[b * 1024 + k];
    int gi = (b << 5) + (k >> 5);
    return (v - st[gi * 2]) * st[gi * 2 + 1] * g[k] + bt[k];
  }
};

struct AfV {  // im2col of raw ctx_map (16x16, pad 1), k = d*9 + dy*3 + dx
  const float* ctx; const float* cmean; const int* cond;
  DINLINE float operator()(int b, int i, int k) const {
    int d = k / 9, r = k - d * 9;
    int dy = r / 3, dx = r - dy * 3;
    int y = (i >> 4) + dy - 1, x = (i & 15) + dx - 1;
    if ((unsigned)y >= 16u || (unsigned)x >= 16u) return 0.f;
    return cond[b] ? ctx[((size_t)b * 256 + y * 16 + x) * 1024 + d] : cmean[b * 1024 + d];
  }
};

struct AfQ {  // [gn(roi); indicator], k in [0,322)
  const float* roix; const float* st; const float* g; const float* bt; const float* ind;
  DINLINE float operator()(int b, int i, int k) const {
    if (i >= 81 || k >= 322) return 0.f;
    if (k >= 320) return ind[b * 2 + (k - 320)];
    float v = roix[((size_t)b * 320 + k) * 81 + i];
    int gi = (b << 5) + (k / 10);
    return (v - st[gi * 2]) * st[gi * 2 + 1] * g[k] + bt[k];
  }
};

struct AfSG {  // im2col of ac (9x9, pad 1), k = d*9 + dy*3 + dx ; ac stored [b][d][p]
  const float* ac;
  DINLINE float operator()(int b, int i, int k) const {
    if (i >= 81) return 0.f;
    int d = k / 9, r = k - d * 9;
    int dy = r / 3, dx = r - dy * 3;
    int py = i / 9;
    int iy = py + dy - 1, ix = (i - py * 9) + dx - 1;
    if ((unsigned)iy >= 9u || (unsigned)ix >= 9u) return 0.f;
    return ac[((size_t)b * 1024 + d) * 81 + iy * 9 + ix];
  }
};

struct AfRow {  // generic row-major per-batch A with i-guard
  const float* p; size_t bs; int ks; int Ireal;
  DINLINE float operator()(int b, int i, int k) const {
    return i < Ireal ? p[b * bs + (size_t)i * ks + k] : 0.f;
  }
};

struct BfW {  // shared weight matrix, row-major [j][k], k-guard
  const float* w; int stride; int Kreal;
  DINLINE float operator()(int, int j, int k) const {
    return k < Kreal ? w[(size_t)j * stride + k] : 0.f;
  }
};

struct BfSgSb {  // concatenated Wsg (j<320) / Wsb weights
  const float* wsg; const float* wsb;
  DINLINE float operator()(int, int j, int k) const {
    return j < 320 ? wsg[(size_t)j * 9216 + k] : wsb[(size_t)(j - 320) * 9216 + k];
  }
};

struct BfBat {  // per-batch row-major B[j][k]
  const float* p; size_t bs; int ks;
  DINLINE float operator()(int b, int j, int k) const { return p[b * bs + (size_t)j * ks + k]; }
};

struct BfTBat {  // per-batch B[j][k] stored transposed: p[k][j]  (use BT=true)
  const float* p; size_t bs; int jstride;
  DINLINE float operator()(int b, int j, int k) const { return p[b * bs + (size_t)k * jstride + j]; }
};

struct BfCtx {  // B[j=d][k=t] = cond ? context[b][t][d] : cmean[b][d]  (use BT=true)
  const float* ctx; const float* cmean; const int* cond;
  DINLINE float operator()(int b, int j, int k) const {
    return cond[b] ? ctx[((size_t)b * 256 + k) * 1024 + j] : cmean[b * 1024 + j];
  }
};

struct CfPlain {  // out[b][i][j] = acc + bias[j]
  float* o; const float* bias; int Ireal; int Jtot;
  DINLINE void operator()(int b, int i, int j, float acc) const {
    o[((size_t)b * Ireal + i) * Jtot + j] = acc + bias[j];
  }
};

struct CfRaw {  // logits -> attn area
  float* o;
  DINLINE void operator()(int b, int i, int j, float acc) const {
    o[((size_t)b * 81 + i) * 256 + j] = acc;
  }
};

struct CfT {  // transposed store out[b][j][i] (81 positions inner)
  float* o; int Jtot;
  DINLINE void operator()(int b, int i, int j, float acc) const {
    o[((size_t)b * Jtot + j) * 81 + i] = acc;
  }
};

struct CfSgSb {
  float* sg; float* sb; const float* bsg; const float* bsb;
  DINLINE void operator()(int b, int i, int j, float acc) const {
    if (j < 320) sg[((size_t)b * 320 + j) * 81 + i] = acc + bsg[j];
    else sb[((size_t)b * 320 + (j - 320)) * 81 + i] = acc + bsb[j - 320];
  }
};

template <bool BT, class AF, class BF, class CF>
__global__ __launch_bounds__(256) void gemm_k(AF af, BF bf, CF cf, int I, int J, int K) {
  const int BI = 32, BJ = 64, BK = 32;
  (void)BI; (void)BJ;
  __shared__ __align__(16) float As[32][36];
  __shared__ __align__(16) float Bs[64][36];
  int b = blockIdx.z;
  int i0 = blockIdx.y * 32, j0 = blockIdx.x * 64;
  int tid = threadIdx.x;
  int ti = (tid >> 4) * 2, tj = (tid & 15) * 4;
  float acc[2][4] = {{0.f, 0.f, 0.f, 0.f}, {0.f, 0.f, 0.f, 0.f}};
  for (int k0 = 0; k0 < K; k0 += BK) {
    __syncthreads();
#pragma unroll
    for (int q = 0; q < 4; ++q) {
      int idx = q * 256 + tid;
      int r = idx >> 5, c = idx & 31;
      As[r][c] = af(b, i0 + r, k0 + c);
    }
#pragma unroll
    for (int q = 0; q < 8; ++q) {
      int idx = q * 256 + tid;
      int r, c;
      if constexpr (BT) { r = idx & 63; c = idx >> 6; }
      else { r = idx >> 5; c = idx & 31; }
      Bs[r][c] = bf(b, j0 + r, k0 + c);
    }
    __syncthreads();
#pragma unroll
    for (int kk = 0; kk < BK; kk += 4) {
      float4 a0 = *(const float4*)&As[ti][kk];
      float4 a1 = *(const float4*)&As[ti + 1][kk];
      float4 b0 = *(const float4*)&Bs[tj][kk];
      float4 b1 = *(const float4*)&Bs[tj + 1][kk];
      float4 b2 = *(const float4*)&Bs[tj + 2][kk];
      float4 b3 = *(const float4*)&Bs[tj + 3][kk];
      acc[0][0] += a0.x * b0.x + a0.y * b0.y + a0.z * b0.z + a0.w * b0.w;
      acc[0][1] += a0.x * b1.x + a0.y * b1.y + a0.z * b1.z + a0.w * b1.w;
      acc[0][2] += a0.x * b2.x + a0.y * b2.y + a0.z * b2.z + a0.w * b2.w;
      acc[0][3] += a0.x * b3.x + a0.y * b3.y + a0.z * b3.z + a0.w * b3.w;
      acc[1][0] += a1.x * b0.x + a1.y * b0.y + a1.z * b0.z + a1.w * b0.w;
      acc[1][1] += a1.x * b1.x + a1.y * b1.y + a1.z * b1.z + a1.w * b1.w;
      acc[1][2] += a1.x * b2.x + a1.y * b2.y + a1.z * b2.z + a1.w * b2.w;
      acc[1][3] += a1.x * b3.x + a1.y * b3.y + a1.z * b3.z + a1.w * b3.w;
    }
  }
#pragma unroll
  for (int ii = 0; ii < 2; ++ii) {
    int i = i0 + ti + ii;
    if (i >= I) continue;
#pragma unroll
    for (int jj = 0; jj < 4; ++jj) cf(b, i, j0 + tj + jj, acc[ii][jj]);
  }
}

// ---------------- launch ----------------

extern "C" void kernel_launch(void* const* d_in, const int* in_sizes, int n_in,
                              void* d_out, int out_size, void* d_ws, size_t ws_size,
                              hipStream_t stream) {
  const float* gx   = (const float*)d_in[0];
  const float* ctx  = (const float*)d_in[1];
  const float* ind  = (const float*)d_in[2];
  const float* bbox = (const float*)d_in[3];
  const int*   cond = (const int*)d_in[4];
  const float* ln_g = (const float*)d_in[5];
  const float* ln_b = (const float*)d_in[6];
  const float* cn_g = (const float*)d_in[7];
  const float* cn_b = (const float*)d_in[8];
  const float* Wq = (const float*)d_in[9];   const float* bq = (const float*)d_in[10];
  const float* Wk = (const float*)d_in[11];  const float* bk = (const float*)d_in[12];
  const float* Wv = (const float*)d_in[13];  const float* bv = (const float*)d_in[14];
  const float* Wsg = (const float*)d_in[15]; const float* bsg = (const float*)d_in[16];
  const float* Wsb = (const float*)d_in[17]; const float* bsb = (const float*)d_in[18];

  float* out = (float*)d_out;
  float* attn = out + (size_t)32 * 320 * 64 * 64;  // second output (B,81,256)

  // scratch arena inside the out region (fully overwritten by k_paste at the end)
  float* k_buf = out;                    // 32*256*320 = 2,621,440
  float* v_buf = k_buf + 2621440;        // 2,621,440
  float* q_buf = v_buf + 2621440;        // 32*81*320 = 829,440
  float* roix  = q_buf + 829440;         // 829,440
  float* ac    = roix + 829440;          // 32*1024*81 = 2,654,208
  float* xa    = ac + 2654208;           // 829,440  ([b][c][p])
  float* sg    = xa + 829440;            // 829,440
  float* sb    = sg + 829440;            // 829,440  (total 12,044,288 < 41,943,040)

  float* cmean = (float*)d_ws;           // 32*1024
  float* cnst  = cmean + 32768;          // 32*32*2
  float* lnst  = cnst + 2048;            // 32*32*2
  float* xast  = lnst + 2048;            // 32*32*2
  float* xloc  = xast + 2048;            // 829,440

  k_ctx_mean<<<dim3(32, 4), 256, 0, stream>>>(ctx, cmean);
  k_cn_stats<<<1024, 256, 0, stream>>>(ctx, cmean, cond, cnst);
  k_roi<<<32, 256, 0, stream>>>(gx, bbox, roix);
  k_stats810<<<1024, 256, 0, stream>>>(roix, lnst, 1e-6f);

  // k = conv1x1(gn(ctx_map)) : per-b GEMM (256 x 320), K=1024
  gemm_k<false><<<dim3(5, 8, 32), 256, 0, stream>>>(
      AfK{ctx, cmean, cnst, cn_g, cn_b, cond}, BfW{Wk, 1024, 1024},
      CfPlain{k_buf, bk, 256, 320}, 256, 320, 1024);
  // v = conv3x3(ctx_map) : (256 x 320), K=9216
  gemm_k<false><<<dim3(5, 8, 32), 256, 0, stream>>>(
      AfV{ctx, cmean, cond}, BfW{Wv, 9216, 9216},
      CfPlain{v_buf, bv, 256, 320}, 256, 320, 9216);
  // q = conv1x1([gn(roi);ind]) : (81 x 320), K=322
  gemm_k<false><<<dim3(5, 3, 32), 256, 0, stream>>>(
      AfQ{roix, lnst, ln_g, ln_b, ind}, BfW{Wq, 322, 322},
      CfPlain{q_buf, bq, 81, 320}, 81, 320, 322);
  // logits = q @ k^T : (81 x 256), K=320  -> attn area
  gemm_k<false><<<dim3(4, 3, 32), 256, 0, stream>>>(
      AfRow{q_buf, (size_t)81 * 320, 320, 81}, BfBat{k_buf, (size_t)256 * 320, 320},
      CfRaw{attn}, 81, 256, 320);
  k_softmax<<<32 * 81, 256, 0, stream>>>(attn);
  // xa = attn @ v : (81 x 320), K=256, B stored transposed
  gemm_k<true><<<dim3(5, 3, 32), 256, 0, stream>>>(
      AfRow{attn, (size_t)81 * 256, 256, 81}, BfTBat{v_buf, (size_t)256 * 320, 320},
      CfT{xa, 320}, 81, 320, 256);
  // ac = attn @ ctx : (81 x 1024), K=256
  gemm_k<true><<<dim3(16, 3, 32), 256, 0, stream>>>(
      AfRow{attn, (size_t)81 * 256, 256, 81}, BfCtx{ctx, cmean, cond},
      CfT{ac, 1024}, 81, 1024, 256);
  k_stats810<<<1024, 256, 0, stream>>>(xa, xast, 1e-5f);
  // sg|sb = conv3x3(ac, Wsg|Wsb) : (81 x 640), K=9216
  gemm_k<false><<<dim3(10, 3, 32), 256, 0, stream>>>(
      AfSG{ac}, BfSgSb{Wsg, Wsb}, CfSgSb{sg, sb, bsg, bsb}, 81, 640, 9216);

  k_combine<<<3240, 256, 0, stream>>>(xa, xast, sg, sb, xloc);
  k_paste<<<10240, 256, 0, stream>>>(gx, bbox, xloc, out);
}

// Round 3
// 560.686 us; speedup vs baseline: 7.7728x; 7.7728x over previous
//
#include <hip/hip_runtime.h>
#include <hip/hip_bf16.h>

#define DINLINE __device__ __forceinline__

typedef short short8 __attribute__((ext_vector_type(8)));
typedef float f32x4 __attribute__((ext_vector_type(4)));
typedef unsigned short u16;

DINLINE u16 f2b(float f) {
  __hip_bfloat16 h = __float2bfloat16(f);
  return *reinterpret_cast<u16*>(&h);
}
DINLINE float b2f(u16 u) {
  __hip_bfloat16 h = *reinterpret_cast<__hip_bfloat16*>(&u);
  return __bfloat162float(h);
}

DINLINE void gload16(const u16* g, u16* l) {
  __builtin_amdgcn_global_load_lds((const __attribute__((address_space(1))) void*)g,
                                   (__attribute__((address_space(3))) void*)l, 16, 0, 0);
}

DINLINE void wave_red2(float& s, float& s2) {
  for (int o = 32; o > 0; o >>= 1) { s += __shfl_down(s, o); s2 += __shfl_down(s2, o); }
}

// ---------------- prep / small kernels ----------------

__global__ void k_ctx_mean(const float* __restrict__ ctx, float* __restrict__ cmean) {
  int b = blockIdx.x;
  int d = blockIdx.y * 256 + threadIdx.x;
  const float* p = ctx + (size_t)b * 256 * 1024 + d;
  float s = 0.f;
  for (int t = 0; t < 256; ++t) s += p[(size_t)t * 1024];
  cmean[b * 1024 + d] = s * (1.f / 256.f);
}

__global__ void k_cn_stats(const float* __restrict__ ctx, const float* __restrict__ cmean,
                           const int* __restrict__ cond, float* __restrict__ stats) {
  int bg = blockIdx.x; int b = bg >> 5, g = bg & 31;
  bool cf = cond[b] != 0;
  float s = 0.f, s2 = 0.f;
  for (int idx = threadIdx.x; idx < 8192; idx += 256) {
    int t = idx >> 5, c = idx & 31;
    float v = cf ? ctx[((size_t)b * 256 + t) * 1024 + g * 32 + c] : cmean[b * 1024 + g * 32 + c];
    s += v; s2 += v * v;
  }
  wave_red2(s, s2);
  __shared__ float sh[4][2];
  int lane = threadIdx.x & 63, w = threadIdx.x >> 6;
  if (lane == 0) { sh[w][0] = s; sh[w][1] = s2; }
  __syncthreads();
  if (threadIdx.x == 0) {
    s = sh[0][0] + sh[1][0] + sh[2][0] + sh[3][0];
    s2 = sh[0][1] + sh[1][1] + sh[2][1] + sh[3][1];
    float m = s * (1.f / 8192.f);
    float var = s2 * (1.f / 8192.f) - m * m;
    stats[bg * 2] = m;
    stats[bg * 2 + 1] = 1.f / sqrtf(var + 1e-6f);
  }
}

// sel (raw bf16), ctxT (raw transposed bf16), cnorm3 (GN'd, triple A-role hi,lo,hi)
__global__ void k_ctx_prep(const float* __restrict__ ctx, const float* __restrict__ cmean,
                           const float* __restrict__ st, const float* __restrict__ cng,
                           const float* __restrict__ cnb, const int* __restrict__ cond,
                           u16* __restrict__ sel, u16* __restrict__ ctxT, u16* __restrict__ cn3) {
  int t = blockIdx.x, b = blockIdx.y;
  bool cf = cond[b] != 0;
#pragma unroll
  for (int q = 0; q < 4; ++q) {
    int d = q * 256 + threadIdx.x;
    float v = cf ? ctx[((size_t)b * 256 + t) * 1024 + d] : cmean[b * 1024 + d];
    u16 sv = f2b(v);
    sel[((size_t)b * 256 + t) * 1024 + d] = sv;
    ctxT[((size_t)b * 1024 + d) * 256 + t] = sv;
    int gi = (b << 5) + (d >> 5);
    float nv = (v - st[gi * 2]) * st[gi * 2 + 1] * cng[d] + cnb[d];
    u16 hi = f2b(nv);
    u16 lo = f2b(nv - b2f(hi));
    size_t base = ((size_t)b * 256 + t) * 3072 + 3 * (size_t)d;
    cn3[base] = hi; cn3[base + 1] = lo; cn3[base + 2] = hi;
  }
}

__global__ void k_roi(const float* __restrict__ gx, const float* __restrict__ bbox,
                      float* __restrict__ roix) {
  int b = blockIdx.x;
  __shared__ int iy0[9], iy1[9], ix0[9], ix1[9];
  __shared__ float fly[9], flx[9];
  int t = threadIdx.x;
  if (t < 9) {
    float x1 = bbox[b * 4 + 0], y1 = bbox[b * 4 + 1], x2 = bbox[b * 4 + 2], y2 = bbox[b * 4 + 3];
    float rw = fmaxf(x2 - x1, 1.f), rh = fmaxf(y2 - y1, 1.f);
    float ctr = ((float)t + 0.5f) / 9.0f;
    float yc = fminf(fmaxf(y1 + ctr * rh, 0.f), 63.f);
    int y0 = (int)floorf(yc);
    iy0[t] = y0; iy1[t] = min(y0 + 1, 63); fly[t] = yc - (float)y0;
    float xc = fminf(fmaxf(x1 + ctr * rw, 0.f), 63.f);
    int x0 = (int)floorf(xc);
    ix0[t] = x0; ix1[t] = min(x0 + 1, 63); flx[t] = xc - (float)x0;
  }
  __syncthreads();
  for (int idx = t; idx < 320 * 81; idx += 256) {
    int c = idx / 81, p = idx - c * 81;
    int py = p / 9, px = p - py * 9;
    const float* img = gx + ((size_t)b * 320 + c) * 4096;
    float ly = fly[py], lx = flx[px];
    float v00 = img[iy0[py] * 64 + ix0[px]];
    float v01 = img[iy0[py] * 64 + ix1[px]];
    float v10 = img[iy1[py] * 64 + ix0[px]];
    float v11 = img[iy1[py] * 64 + ix1[px]];
    roix[((size_t)b * 320 + c) * 81 + p] =
        v00 * (1.f - ly) * (1.f - lx) + v01 * (1.f - ly) * lx + v10 * ly * (1.f - lx) + v11 * ly * lx;
  }
}

__global__ void k_stats810(const float* __restrict__ src, float* __restrict__ stats, float eps) {
  int bg = blockIdx.x;
  const float* p = src + (size_t)bg * 810;
  float s = 0.f, s2 = 0.f;
  for (int i = threadIdx.x; i < 810; i += 256) { float v = p[i]; s += v; s2 += v * v; }
  wave_red2(s, s2);
  __shared__ float sh[4][2];
  int lane = threadIdx.x & 63, w = threadIdx.x >> 6;
  if (lane == 0) { sh[w][0] = s; sh[w][1] = s2; }
  __syncthreads();
  if (threadIdx.x == 0) {
    s = sh[0][0] + sh[1][0] + sh[2][0] + sh[3][0];
    s2 = sh[0][1] + sh[1][1] + sh[2][1] + sh[3][1];
    float m = s * (1.f / 810.f);
    float var = s2 * (1.f / 810.f) - m * m;
    stats[bg * 2] = m;
    stats[bg * 2 + 1] = 1.f / sqrtf(var + eps);
  }
}

// Aq3 [4096][1152] triple A-role: gn(roi) | indicator | zero-pad
__global__ void k_aq3(const float* __restrict__ roix, const float* __restrict__ st,
                      const float* __restrict__ lng, const float* __restrict__ lnb,
                      const float* __restrict__ ind, u16* __restrict__ o) {
  int i = blockIdx.x * 256 + threadIdx.x;
  if (i >= 32 * 128 * 384) return;
  int b = i / (128 * 384), rem = i - b * 128 * 384;
  int row = rem / 384, k = rem - row * 384;
  float v = 0.f;
  if (row < 81) {
    if (k < 320) {
      float x = roix[((size_t)b * 320 + k) * 81 + row];
      int gi = (b << 5) + k / 10;
      v = (x - st[gi * 2]) * st[gi * 2 + 1] * lng[k] + lnb[k];
    } else if (k < 322) v = ind[b * 2 + (k - 320)];
  }
  u16 hi = f2b(v);
  u16 lo = f2b(v - b2f(hi));
  size_t base = ((size_t)b * 128 + row) * 1152 + 3 * (size_t)k;
  o[base] = hi; o[base + 1] = lo; o[base + 2] = hi;
}

// weight conversions
__global__ void k_cvt_wk3(const float* __restrict__ w, u16* __restrict__ o) {  // [320][1024] -> triple B-role
  int i = blockIdx.x * 256 + threadIdx.x;
  if (i >= 320 * 1024) return;
  int c = i / 1024, d = i - c * 1024;
  float v = w[i];
  u16 hi = f2b(v);
  u16 lo = f2b(v - b2f(hi));
  size_t base = (size_t)c * 3072 + 3 * (size_t)d;
  o[base] = hi; o[base + 1] = hi; o[base + 2] = lo;
}
__global__ void k_cvt_wq3(const float* __restrict__ w, u16* __restrict__ o) {  // [320][322] -> [320][1152] triple B-role
  int i = blockIdx.x * 256 + threadIdx.x;
  if (i >= 320 * 384) return;
  int c = i / 384, k = i - c * 384;
  float v = (k < 322) ? w[c * 322 + k] : 0.f;
  u16 hi = f2b(v);
  u16 lo = f2b(v - b2f(hi));
  size_t base = (size_t)c * 1152 + 3 * (size_t)k;
  o[base] = hi; o[base + 1] = hi; o[base + 2] = lo;
}
// [C][1024*9] (d*9+r) -> [C][9*1024] (r*1024+d) bf16
__global__ void k_cvt_reorder9(const float* __restrict__ w, u16* __restrict__ o) {
  int i = blockIdx.x * 256 + threadIdx.x;
  if (i >= 320 * 9216) return;
  int c = i / 9216, rem = i - c * 9216;
  int r = rem / 1024, d = rem - r * 1024;
  o[i] = f2b(w[(size_t)c * 9216 + d * 9 + r]);
}

__global__ void k_softmax2(float* __restrict__ attn, u16* __restrict__ attn_bf) {
  int i = blockIdx.x, b = blockIdx.y;
  int t = threadIdx.x;
  if (i >= 81) { attn_bf[((size_t)b * 128 + i) * 256 + t] = 0; return; }
  float* p = attn + ((size_t)b * 81 + i) * 256;
  float v = p[t];
  float m = v;
  for (int o = 32; o > 0; o >>= 1) m = fmaxf(m, __shfl_down(m, o));
  __shared__ float sm[4], ss[4];
  if ((t & 63) == 0) sm[t >> 6] = m;
  __syncthreads();
  m = fmaxf(fmaxf(sm[0], sm[1]), fmaxf(sm[2], sm[3]));
  float e = expf(v - m);
  float s = e;
  for (int o = 32; o > 0; o >>= 1) s += __shfl_down(s, o);
  if ((t & 63) == 0) ss[t >> 6] = s;
  __syncthreads();
  s = ss[0] + ss[1] + ss[2] + ss[3];
  float r = e / s;
  p[t] = r;
  attn_bf[((size_t)b * 128 + i) * 256 + t] = f2b(r);
}

__global__ void k_combine(const float* __restrict__ xa, const float* __restrict__ st,
                          const float* __restrict__ sg, const float* __restrict__ sb,
                          float* __restrict__ xl) {
  int idx = blockIdx.x * 256 + threadIdx.x;
  if (idx >= 32 * 320 * 81) return;
  int bc = idx / 81;
  int c = bc % 320, b = bc / 320;
  int g = c / 10;
  float m = st[(b * 32 + g) * 2], rs = st[(b * 32 + g) * 2 + 1];
  xl[idx] = (xa[idx] - m) * rs * sg[idx] + sb[idx];
}

__global__ void k_paste(const float* __restrict__ gx, const float* __restrict__ bbox,
                        const float* __restrict__ xl, float* __restrict__ out) {
  int bc = blockIdx.x;
  int b = bc / 320;
  __shared__ int sy[64], sx[64];
  __shared__ unsigned char my[64], mx[64];
  int x1b = (int)floorf(bbox[b * 4 + 0] * 64.f);
  int y1b = (int)floorf(bbox[b * 4 + 1] * 64.f);
  int x2b = max((int)floorf(bbox[b * 4 + 2] * 64.f), x1b + 1);
  int y2b = max((int)floorf(bbox[b * 4 + 3] * 64.f), y1b + 1);
  int t = threadIdx.x;
  if (t < 64) {
    int jy = t - y1b, oh = y2b - y1b;
    my[t] = (jy >= 0 && t < y2b) ? 1 : 0;
    sy[t] = my[t] ? min(jy * 9 / oh, 8) : 0;
    int jx = t - x1b, ow = x2b - x1b;
    mx[t] = (jx >= 0 && t < x2b) ? 1 : 0;
    sx[t] = mx[t] ? min(jx * 9 / ow, 8) : 0;
  }
  __syncthreads();
  size_t base = (size_t)bc * 4096;
  const float* xlb = xl + (size_t)bc * 81;
  for (int idx = t; idx < 4096; idx += 256) {
    int y = idx >> 6, x = idx & 63;
    float add = (my[y] && mx[x]) ? xlb[sy[y] * 9 + sx[x]] : 0.f;
    out[base + idx] = gx[base + idx] + add;
  }
}

// ---------------- MFMA GEMM: C[b][i][j] = sum_k A(b,i,k)*B(b,j,k) ----------------
// BM=BN=64, BK=64, 4 waves, 16x16x32 bf16 MFMA, global_load_lds staging,
// XOR-swizzled LDS via pre-swizzled global source column.

struct LinA {  // row-major [.][K] with batch stride bs rows
  const u16* A; long bs; int K;
  struct RS { const u16* base; };
  DINLINE RS row(int b, int p) const { return { A + ((long)b * bs + p) * K }; }
  DINLINE const u16* ptr(const RS& rs, int kk) const { return rs.base + (kk << 6); }
};

// 3x3-shift A source: logical K = 9*1024, slot s=kk>>4 picks (dy,dx), row remap with zero page
template <int H, int W, int RB>
struct ShiftA {
  const u16* src; const u16* zp;
  struct RS { int y, x; const u16* bbase; int pin; };
  DINLINE RS row(int b, int p) const {
    int y = p / W, x = p - y * W;
    return { y, x, src + (long)b * RB * 1024, p < H * W ? 1 : 0 };
  }
  DINLINE const u16* ptr(const RS& rs, int kk) const {
    int s = kk >> 4, d0 = (kk & 15) << 6;
    int sy = (s * 11) >> 5;           // s/3 for s<9
    int sx = s - sy * 3;
    int yy = rs.y + sy - 1, xx = rs.x + sx - 1;
    bool ok = rs.pin && ((unsigned)yy < (unsigned)H) && ((unsigned)xx < (unsigned)W);
    return ok ? rs.bbase + (((long)(yy * W + xx)) << 10) + d0 : zp;
  }
};

struct EpiK3 {  // k3 [8192][960] triple B-role
  u16* o; const float* bias;
  DINLINE void operator()(int, int i, int j, float v) const {
    v += bias[j];
    u16 hi = f2b(v), lo = f2b(v - b2f(hi));
    size_t base = (size_t)i * 960 + 3 * (size_t)j;
    o[base] = hi; o[base + 1] = hi; o[base + 2] = lo;
  }
};
struct EpiQ3 {  // q3 [4096][960] triple A-role
  u16* o; const float* bias;
  DINLINE void operator()(int, int i, int j, float v) const {
    v += bias[j];
    u16 hi = f2b(v), lo = f2b(v - b2f(hi));
    size_t base = (size_t)i * 960 + 3 * (size_t)j;
    o[base] = hi; o[base + 1] = lo; o[base + 2] = hi;
  }
};
struct EpiVT {  // vT[b][c][t] bf16
  u16* vT; const float* bv;
  DINLINE void operator()(int b, int i, int j, float v) const {
    vT[((size_t)b * 320 + j) * 256 + i] = f2b(v + bv[j]);
  }
};
struct EpiLogits {
  float* attn;
  DINLINE void operator()(int b, int i, int j, float v) const {
    if (i < 81) attn[((size_t)b * 81 + i) * 256 + j] = v;
  }
};
struct EpiXa {
  float* xa;
  DINLINE void operator()(int b, int i, int j, float v) const {
    if (i < 81) xa[((size_t)b * 320 + j) * 81 + i] = v;
  }
};
struct EpiAc {  // ac [b][128][1024] bf16
  u16* ac;
  DINLINE void operator()(int b, int i, int j, float v) const {
    ac[((size_t)b * 128 + i) * 1024 + j] = f2b(v);
  }
};
struct EpiSgSb {
  float* sg; float* sb; const float* bsg; const float* bsb;
  DINLINE void operator()(int b, int i, int j, float v) const {
    if (i >= 81) return;
    if (j < 320) sg[((size_t)b * 320 + j) * 81 + i] = v + bsg[j];
    else sb[((size_t)b * 320 + (j - 320)) * 81 + i] = v + bsb[j - 320];
  }
};

template <class ASRC, class EPI>
__global__ __launch_bounds__(256, 2) void mfma_gemm(ASRC asrc, const u16* __restrict__ B,
                                                    long b_bs, int K, EPI epi) {
  __shared__ u16 As[4096];
  __shared__ u16 Bs[4096];
  const int tid = threadIdx.x;
  const int w = tid >> 6, l = tid & 63;
  const int wm = w >> 1, wn = w & 1;
  const int b = blockIdx.z;
  const int p0 = blockIdx.y * 64;
  const long j0 = (long)blockIdx.x * 64 + (long)b * b_bs;

  const int r0 = w * 16 + (l >> 3);
  const int csw = (((l & 7) ^ ((l >> 3) & 7)) << 3);  // pre-swizzled source column (elems)
  auto rsA0 = asrc.row(b, p0 + r0);
  auto rsA1 = asrc.row(b, p0 + r0 + 8);
  const u16* gB0 = B + (j0 + r0) * K + csw;
  const u16* gB1 = gB0 + 8 * (long)K;
  u16* lA0 = As + w * 1024; u16* lA1 = lA0 + 512;
  u16* lB0 = Bs + w * 1024; u16* lB1 = lB0 + 512;

  f32x4 acc[2][2];
#pragma unroll
  for (int a = 0; a < 2; ++a)
#pragma unroll
    for (int c = 0; c < 2; ++c) acc[a][c] = (f32x4){0.f, 0.f, 0.f, 0.f};

  const int fr = l & 15, fs = l >> 4, fx = l & 7;
  const int arow = wm * 32 + fr, brow = wn * 32 + fr;

  const int nk = K >> 6;
  for (int kk = 0; kk < nk; ++kk) {
    __syncthreads();
    gload16(asrc.ptr(rsA0, kk) + csw, lA0);
    gload16(asrc.ptr(rsA1, kk) + csw, lA1);
    gload16(gB0, lB0); gload16(gB1, lB1);
    gB0 += 64; gB1 += 64;
    __syncthreads();
    short8 af[2][2], bf[2][2];
#pragma unroll
    for (int fm = 0; fm < 2; ++fm) {
      int row = arow + fm * 16;
#pragma unroll
      for (int kh = 0; kh < 2; ++kh) {
        int slot = ((kh << 2) | fs) ^ fx;
        af[fm][kh] = *(const short8*)(As + row * 64 + slot * 8);
      }
    }
#pragma unroll
    for (int fn = 0; fn < 2; ++fn) {
      int row = brow + fn * 16;
#pragma unroll
      for (int kh = 0; kh < 2; ++kh) {
        int slot = ((kh << 2) | fs) ^ fx;
        bf[fn][kh] = *(const short8*)(Bs + row * 64 + slot * 8);
      }
    }
#pragma unroll
    for (int kh = 0; kh < 2; ++kh)
#pragma unroll
      for (int fm = 0; fm < 2; ++fm)
#pragma unroll
        for (int fn = 0; fn < 2; ++fn)
          acc[fm][fn] = __builtin_amdgcn_mfma_f32_16x16x32_bf16(af[fm][kh], bf[fn][kh], acc[fm][fn], 0, 0, 0);
  }

  const int ib = wm * 32 + fs * 4;
  const int jb = wn * 32 + fr;
#pragma unroll
  for (int fm = 0; fm < 2; ++fm)
#pragma unroll
    for (int fn = 0; fn < 2; ++fn)
#pragma unroll
      for (int r = 0; r < 4; ++r)
        epi(b, p0 + ib + fm * 16 + r, blockIdx.x * 64 + jb + fn * 16, acc[fm][fn][r]);
}

// ---------------- launch ----------------

extern "C" void kernel_launch(void* const* d_in, const int* in_sizes, int n_in,
                              void* d_out, int out_size, void* d_ws, size_t ws_size,
                              hipStream_t stream) {
  const float* gx   = (const float*)d_in[0];
  const float* ctx  = (const float*)d_in[1];
  const float* ind  = (const float*)d_in[2];
  const float* bbox = (const float*)d_in[3];
  const int*   cond = (const int*)d_in[4];
  const float* ln_g = (const float*)d_in[5];
  const float* ln_b = (const float*)d_in[6];
  const float* cn_g = (const float*)d_in[7];
  const float* cn_b = (const float*)d_in[8];
  const float* Wq = (const float*)d_in[9];   const float* bq = (const float*)d_in[10];
  const float* Wk = (const float*)d_in[11];  const float* bk = (const float*)d_in[12];
  const float* Wv = (const float*)d_in[13];  const float* bv = (const float*)d_in[14];
  const float* Wsg = (const float*)d_in[15]; const float* bsg = (const float*)d_in[16];
  const float* Wsb = (const float*)d_in[17]; const float* bsb = (const float*)d_in[18];

  char* base = (char*)d_out;
  float* out = (float*)d_out;
  float* attn_out = out + (size_t)41943040;  // second output (B,81,256) fp32

  // arena inside first output region (167,772,160 B), fully overwritten by k_paste
  u16* sel     = (u16*)(base + 0);            // [32][256][1024]      16,777,216
  u16* ctxT    = (u16*)(base + 16777216);     // [32][1024][256]      16,777,216
  u16* cn3     = (u16*)(base + 33554432);     // [8192][3072]         50,331,648
  u16* k3      = (u16*)(base + 83886080);     // [8192][960]          15,728,640
  u16* Aq3     = (u16*)(base + 99614720);     // [4096][1152]          9,437,184
  u16* q3      = (u16*)(base + 109051904);    // [4096][960]           7,864,320
  u16* attn_bf = (u16*)(base + 116916224);    // [32][128][256]        2,097,152
  u16* vT      = (u16*)(base + 119013376);    // [32][320][256]        5,242,880
  u16* ac_bf   = (u16*)(base + 124256256);    // [32][128][1024]       8,388,608
  float* xa_f  = (float*)(base + 132644864);  // [32][320][81]         3,317,760
  float* sg_f  = (float*)(base + 135962624);  //                       3,317,760
  float* sb_f  = (float*)(base + 139280384);  //                       3,317,760
  u16* Wk3     = (u16*)(base + 142598144);    // [320][3072]           1,966,080
  u16* Wq3     = (u16*)(base + 144564224);    // [320][1152]             737,280
  u16* Wv_r    = (u16*)(base + 145301504);    // [320][9216]           5,898,240
  u16* Wsgsb   = (u16*)(base + 151199744);    // [640][9216]          11,796,480  (ends 162,996,224)

  float* cmean = (float*)d_ws;            // 32768 f
  float* cnst  = cmean + 32768;           // 2048 f
  float* lnst  = cnst + 2048;             // 2048 f
  float* xast  = lnst + 2048;             // 2048 f
  float* roix  = xast + 2048;             // 829440 f
  float* xloc  = roix + 829440;           // 829440 f
  u16*   zpage = (u16*)(xloc + 829440);   // 4096 B zero page

  hipMemsetAsync((void*)zpage, 0, 4096, stream);

  // prep
  k_ctx_mean<<<dim3(32, 4), 256, 0, stream>>>(ctx, cmean);
  k_cn_stats<<<1024, 256, 0, stream>>>(ctx, cmean, cond, cnst);
  k_ctx_prep<<<dim3(256, 32), 256, 0, stream>>>(ctx, cmean, cnst, cn_g, cn_b, cond, sel, ctxT, cn3);
  k_roi<<<32, 256, 0, stream>>>(gx, bbox, roix);
  k_stats810<<<1024, 256, 0, stream>>>(roix, lnst, 1e-6f);
  k_aq3<<<6144, 256, 0, stream>>>(roix, lnst, ln_g, ln_b, ind, Aq3);
  k_cvt_wk3<<<1280, 256, 0, stream>>>(Wk, Wk3);
  k_cvt_wq3<<<480, 256, 0, stream>>>(Wq, Wq3);
  k_cvt_reorder9<<<11520, 256, 0, stream>>>(Wv, Wv_r);
  k_cvt_reorder9<<<11520, 256, 0, stream>>>(Wsg, Wsgsb);
  k_cvt_reorder9<<<11520, 256, 0, stream>>>(Wsb, Wsgsb + (size_t)320 * 9216);

  // K-proj (split-fp32): [8192][3072] x [320][3072] -> k3 triple
  mfma_gemm<<<dim3(5, 128, 1), 256, 0, stream>>>(LinA{cn3, 0, 3072}, Wk3, 0L, 3072,
                                                 EpiK3{k3, bk});
  // V conv: on-the-fly 3x3 shift over sel, K=9216 -> vT bf16
  mfma_gemm<<<dim3(5, 4, 32), 256, 0, stream>>>(ShiftA<16, 16, 256>{sel, zpage}, Wv_r, 0L, 9216,
                                                EpiVT{vT, bv});
  // Q-proj (split-fp32): [4096][1152] x [320][1152] -> q3 triple
  mfma_gemm<<<dim3(5, 64, 1), 256, 0, stream>>>(LinA{Aq3, 0, 1152}, Wq3, 0L, 1152,
                                                EpiQ3{q3, bq});
  // logits (split-fp32): per-batch q3[128][960] x k3[256][960] -> fp32 attn
  mfma_gemm<<<dim3(4, 2, 32), 256, 0, stream>>>(LinA{q3, 128, 960}, k3, 256L, 960,
                                                EpiLogits{attn_out});
  k_softmax2<<<dim3(128, 32), 256, 0, stream>>>(attn_out, attn_bf);
  // xa = attn @ v : per-batch [128][256] x vT[320][256]
  mfma_gemm<<<dim3(5, 2, 32), 256, 0, stream>>>(LinA{attn_bf, 128, 256}, vT, 320L, 256,
                                                EpiXa{xa_f});
  // ac = attn @ ctx : per-batch [128][256] x ctxT[1024][256]
  mfma_gemm<<<dim3(16, 2, 32), 256, 0, stream>>>(LinA{attn_bf, 128, 256}, ctxT, 1024L, 256,
                                                 EpiAc{ac_bf});
  k_stats810<<<1024, 256, 0, stream>>>(xa_f, xast, 1e-5f);
  // SG/SB conv: on-the-fly 3x3 shift over ac (9x9), K=9216, j=[sg|sb]
  mfma_gemm<<<dim3(10, 2, 32), 256, 0, stream>>>(ShiftA<9, 9, 128>{ac_bf, zpage}, Wsgsb, 0L, 9216,
                                                 EpiSgSb{sg_f, sb_f, bsg, bsb});

  k_combine<<<3240, 256, 0, stream>>>(xa_f, xast, sg_f, sb_f, xloc);
  k_paste<<<10240, 256, 0, stream>>>(gx, bbox, xloc, out);
}